// Round 9
// baseline (129.555 us; speedup 1.0000x reference)
//
#include <hip/hip_runtime.h>
#include <math.h>

#define NPAIR  2
#define KDIM   64
#define NKP    400
#define NTILE  28            /* keypoint 16-tiles (448 padded) */
#define HWPIX  65536
#define MREF   70.0f         /* fixed softmax reference: logits = 100*cos <= 100 */
#define LOG2E  1.44269504f

/* ws layout (dwords):
   [0, BFRAG_DW)  : tgt B-fragments [p][nt][ks][hi/lo][lane][4dw], bf16 pairs
   [BFRAG_DW, ..) : partials [p][nt][512 mb][16 j] float2 {S, U_local(0..127)} */
#define BFRAG_DW (NPAIR*NTILE*2*2*256)   /* 57344 dwords */

using frag_ab = __attribute__((ext_vector_type(8))) short;   // 8 bf16
using f32x4   = __attribute__((ext_vector_type(4))) float;

__device__ __forceinline__ unsigned short f2bf(float f){
    unsigned u = __builtin_bit_cast(unsigned, f);
    u += 0x7fffu + ((u >> 16) & 1u);          // round-to-nearest-even
    return (unsigned short)(u >> 16);
}
__device__ __forceinline__ float bf2f(unsigned short h){
    unsigned u = ((unsigned)h) << 16;
    return __builtin_bit_cast(float, u);
}
/* async 16B global->LDS DMA: lds dst = wave-uniform base + lane*16 */
__device__ __forceinline__ void async16(unsigned* lds, const unsigned* g){
    __builtin_amdgcn_global_load_lds(
        (const __attribute__((address_space(1))) unsigned*)g,
        (__attribute__((address_space(3))) unsigned*)lds, 16, 0, 0);
}

/* normalize tgt desc, split to bf16 hi/lo, store in MFMA B-frag order
   (n = lane&15, k = (lane>>4)*8 + j). */
__global__ __launch_bounds__(256) void prep_kernel(
    const float* __restrict__ ksc, const float* __restrict__ kd,
    const int* __restrict__ tgt_ids, const int* __restrict__ src_ids,
    unsigned* __restrict__ wsu, float* __restrict__ out)
{
    __shared__ float xs[KDIM][33];
    __shared__ float inv_s[32];
    int d = blockIdx.x, p = blockIdx.y, t = threadIdx.x;
    int tgt = tgt_ids[p];
    int nl = t & 31, c0 = t >> 5;
    #pragma unroll
    for (int cc = 0; cc < 8; ++cc){
        int c = cc*8 + c0;
        int n = d*32 + nl;
        xs[c][nl] = (n < NKP) ? kd[(tgt*KDIM + c)*NKP + n] : 0.f;
    }
    __syncthreads();
    if (t < 32){
        float s = 0.f;
        #pragma unroll
        for (int c = 0; c < KDIM; ++c){ float v = xs[c][t]; s = fmaf(v, v, s); }
        inv_s[t] = 1.f / fmaxf(sqrtf(s), 1e-12f);
    }
    __syncthreads();
    {
        int l = t & 63, rk = t >> 6;
        int rt = rk >> 1, ks = rk & 1;
        int cl = l & 15, g = l >> 4;
        int nloc = rt*16 + cl;
        float inv = inv_s[nloc];
        int k0 = ks*32 + g*8;
        unsigned hu[4], lu[4];
        #pragma unroll
        for (int j2 = 0; j2 < 4; ++j2){
            float xa = xs[k0 + 2*j2    ][nloc] * inv;
            float xb = xs[k0 + 2*j2 + 1][nloc] * inv;
            unsigned short ha = f2bf(xa), hb = f2bf(xb);
            unsigned short la = f2bf(xa - bf2f(ha)), lb = f2bf(xb - bf2f(hb));
            hu[j2] = (unsigned)ha | ((unsigned)hb << 16);
            lu[j2] = (unsigned)la | ((unsigned)lb << 16);
        }
        int nt = d*2 + rt;
        unsigned base = (unsigned)(((p*NTILE + nt)*2 + ks)*2)*256 + l*4;
        *(uint4*)&wsu[base]       = make_uint4(hu[0], hu[1], hu[2], hu[3]);
        *(uint4*)&wsu[base + 256] = make_uint4(lu[0], lu[1], lu[2], lu[3]);
    }
    if (t < 32){
        int n = d*32 + t;
        if (n < NKP) out[NPAIR*NKP*2 + p*NKP + n] = ksc[tgt*NKP + n];
    }
    if (d == 0 && t == 0){
        out[NPAIR*NKP*3 + p]         = (float)tgt;
        out[NPAIR*NKP*3 + NPAIR + p] = (float)src_ids[p];
    }
}

/* one block per (pair, 128-pixel block). A (pixels) loaded direct to regs
   (no staging buffer); B (keypoints) block-shared via async global->LDS DMA,
   4-slot ring, 2 nt per barrier. Softmax reduce over pixels = register dim
   + 2 shfl; per-wave partials in LDS, one end-of-kernel cross-wave sum. */
__global__ __launch_bounds__(256, 4) void match_kernel(
    const float* __restrict__ dd, const int* __restrict__ src_ids,
    const unsigned* __restrict__ wsu, float* __restrict__ part)
{
    __shared__ unsigned Bst[4][1024];          // 16 KB B ring
    __shared__ float invn_s[128];
    __shared__ float wp[4*NTILE*16*2];         // 14 KB wave-partials
    int mb = blockIdx.x, p = blockIdx.y, t = threadIdx.x;
    int w = t >> 6, l = t & 63;
    int cl = l & 15, g = l >> 4;
    int mloc0 = w*32;

    const unsigned* wBp = wsu + (unsigned)p*(NTILE*1024) + (unsigned)t*4;
    auto bload = [&](int nt){
        async16(&Bst[nt & 3][(unsigned)w*256], wBp + (unsigned)nt*1024);
    };

    /* B(0), B(1) DMA issue first (covered by the one staging barrier) */
    bload(0); bload(1);

    /* direct A load: lane (cl,g) owns pixel mloc0+mt*16+cl, k = ks*32+g*8+j.
       Split raw to bf16 hi/lo in-register; ssum via butterfly over g. */
    const float* ap = dd + (size_t)src_ids[p]*KDIM*HWPIX + (size_t)mb*128
                    + (unsigned)(mloc0 + cl);
    uint4 Ac[2][4];                 // [mt][ks*2 + hi/lo]
    #pragma unroll
    for (int mt = 0; mt < 2; ++mt){
        float ss = 0.f;
        #pragma unroll
        for (int ks = 0; ks < 2; ++ks){
            float v[8];
            #pragma unroll
            for (int j = 0; j < 8; ++j)
                v[j] = ap[(size_t)(ks*32 + g*8 + j)*HWPIX + mt*16];
            unsigned hq[4], lq[4];
            #pragma unroll
            for (int q = 0; q < 4; ++q){
                float a = v[2*q], b = v[2*q+1];
                ss = fmaf(a, a, ss);
                ss = fmaf(b, b, ss);
                unsigned ta = (__builtin_bit_cast(unsigned, a) + 0x8000u) & 0xFFFF0000u;
                unsigned tb = (__builtin_bit_cast(unsigned, b) + 0x8000u) & 0xFFFF0000u;
                float la = a - __builtin_bit_cast(float, ta);
                float lb = b - __builtin_bit_cast(float, tb);
                hq[q] = __builtin_amdgcn_perm(tb, ta, 0x07060302u);
                lq[q] = __builtin_amdgcn_perm(__builtin_bit_cast(unsigned, lb),
                                              __builtin_bit_cast(unsigned, la), 0x07060302u);
            }
            Ac[mt][ks*2 + 0] = make_uint4(hq[0], hq[1], hq[2], hq[3]);
            Ac[mt][ks*2 + 1] = make_uint4(lq[0], lq[1], lq[2], lq[3]);
        }
        ss += __shfl_xor(ss, 16);
        ss += __shfl_xor(ss, 32);
        if (g == 0)
            invn_s[mloc0 + mt*16 + cl] = (100.f*LOG2E) / fmaxf(sqrtf(ss), 1e-12f);
    }
    __syncthreads();   /* drains B(0),B(1) DMA + publishes invn_s */

    const float mref2 = MREF * LOG2E;
    float invm8[2][4], ub2[2];
    #pragma unroll
    for (int mt = 0; mt < 2; ++mt){
        ub2[mt] = (float)(mloc0 + mt*16 + g*4);
        #pragma unroll
        for (int r = 0; r < 4; ++r)
            invm8[mt][r] = invn_s[mloc0 + mt*16 + g*4 + r];
    }

    f32x4 acc0[2], acc1[2];
    auto zacc = [&](f32x4* a){
        a[0] = (f32x4){0.f,0.f,0.f,0.f};
        a[1] = (f32x4){0.f,0.f,0.f,0.f};
    };
    auto unit = [&](int nt, f32x4* a2){
        const unsigned* Bb = &Bst[nt & 3][0];
        #pragma unroll
        for (int ks = 0; ks < 2; ++ks){
            frag_ab bH  = __builtin_bit_cast(frag_ab, *(const uint4*)&Bb[(ks*2+0)*256 + l*4]);
            frag_ab bL  = __builtin_bit_cast(frag_ab, *(const uint4*)&Bb[(ks*2+1)*256 + l*4]);
            frag_ab a0H = __builtin_bit_cast(frag_ab, Ac[0][ks*2]);
            frag_ab a0L = __builtin_bit_cast(frag_ab, Ac[0][ks*2 + 1]);
            frag_ab a1H = __builtin_bit_cast(frag_ab, Ac[1][ks*2]);
            frag_ab a1L = __builtin_bit_cast(frag_ab, Ac[1][ks*2 + 1]);
            a2[0] = __builtin_amdgcn_mfma_f32_16x16x32_bf16(a0H, bH, a2[0], 0, 0, 0);
            a2[1] = __builtin_amdgcn_mfma_f32_16x16x32_bf16(a1H, bH, a2[1], 0, 0, 0);
            a2[0] = __builtin_amdgcn_mfma_f32_16x16x32_bf16(a0H, bL, a2[0], 0, 0, 0);
            a2[1] = __builtin_amdgcn_mfma_f32_16x16x32_bf16(a1H, bL, a2[1], 0, 0, 0);
            a2[0] = __builtin_amdgcn_mfma_f32_16x16x32_bf16(a0L, bH, a2[0], 0, 0, 0);
            a2[1] = __builtin_amdgcn_mfma_f32_16x16x32_bf16(a1L, bH, a2[1], 0, 0, 0);
        }
    };
    auto epi = [&](const f32x4* a2, int nt){
        float Ssum = 0.f, Usum = 0.f;
        #pragma unroll
        for (int mt = 0; mt < 2; ++mt){
            float e0 = __builtin_amdgcn_exp2f(fmaf(a2[mt][0], invm8[mt][0], -mref2));
            float e1 = __builtin_amdgcn_exp2f(fmaf(a2[mt][1], invm8[mt][1], -mref2));
            float e2 = __builtin_amdgcn_exp2f(fmaf(a2[mt][2], invm8[mt][2], -mref2));
            float e3 = __builtin_amdgcn_exp2f(fmaf(a2[mt][3], invm8[mt][3], -mref2));
            float Sm = (e0 + e1) + (e2 + e3);
            float Um = fmaf(e2, 2.f, e1);
            Um = fmaf(e3, 3.f, Um);
            Um = fmaf(ub2[mt], Sm, Um);
            Ssum += Sm; Usum += Um;
        }
        Ssum += __shfl_xor(Ssum, 16); Usum += __shfl_xor(Usum, 16);
        Ssum += __shfl_xor(Ssum, 32); Usum += __shfl_xor(Usum, 32);
        if (l < 16)
            *(float2*)&wp[((unsigned)(w*NTILE + nt)*16 + (unsigned)l)*2] =
                make_float2(Ssum, Usum);
    };

    /* main loop: 2 nt per barrier, B ring prefetched 2 ahead */
    #pragma unroll 1
    for (int j = 0; j < 14; ++j){
        if (j < 13){ bload(2*j + 2); bload(2*j + 3); }
        zacc(acc0); unit(2*j,     acc0);
        zacc(acc1); unit(2*j + 1, acc1);
        epi(acc0, 2*j);
        epi(acc1, 2*j + 1);
        __syncthreads();
    }

    /* cross-wave sum of the 4 wave-partials -> global compact partials */
    for (int idx = t; idx < NTILE*16; idx += 256){
        int nt = idx >> 4, cc = idx & 15;
        float S = 0.f, U = 0.f;
        #pragma unroll
        for (int ww = 0; ww < 4; ++ww){
            float2 q = *(const float2*)&wp[((unsigned)(ww*NTILE + nt)*16 + (unsigned)cc)*2];
            S += q.x; U += q.y;
        }
        *(float2*)&part[(((size_t)p*NTILE + nt)*512 + mb)*32 + cc*2] =
            make_float2(S, U);
    }
}

/* one block per (p, nt<25): fully-coalesced float2 reads, LDS cross-wave sum */
__global__ __launch_bounds__(256) void merge_kernel(
    const float* __restrict__ part, float* __restrict__ out)
{
    __shared__ float red[3][4][16];
    int nt = blockIdx.x, p = blockIdx.y, t = threadIdx.x;
    int j = t & 15, mb0 = t >> 4;
    const float* base = part + ((size_t)(p*NTILE + nt)*512)*32;
    float S = 0.f, U = 0.f, V = 0.f;
    #pragma unroll 4
    for (int k = 0; k < 32; ++k){
        int mbk = mb0 + k*16;
        float2 q = *(const float2*)&base[(mbk*16 + j)*2];
        S += q.x;
        U += q.y + (float)((mbk & 1)*128)*q.x;
        V = fmaf((float)(mbk >> 1), q.x, V);
    }
    S += __shfl_xor(S, 16); U += __shfl_xor(U, 16); V += __shfl_xor(V, 16);
    S += __shfl_xor(S, 32); U += __shfl_xor(U, 32); V += __shfl_xor(V, 32);
    int w = t >> 6, l = t & 63;
    if (l < 16){ red[0][w][j] = S; red[1][w][j] = U; red[2][w][j] = V; }
    __syncthreads();
    if (t < 16){
        float Sf = red[0][0][t] + red[0][1][t] + red[0][2][t] + red[0][3][t];
        float Uf = red[1][0][t] + red[1][1][t] + red[1][2][t] + red[1][3][t];
        float Vf = red[2][0][t] + red[2][1][t] + red[2][2][t] + red[2][3][t];
        int n = nt*16 + t;
        out[(p*NKP + n)*2 + 0] = Uf / Sf;
        out[(p*NKP + n)*2 + 1] = Vf / Sf;
    }
}

extern "C" void kernel_launch(void* const* d_in, const int* in_sizes, int n_in,
                              void* d_out, int out_size, void* d_ws, size_t ws_size,
                              hipStream_t stream)
{
    const float* ksc     = (const float*)d_in[0];  // keypoint_scores [4,1,400]
    const float* kd      = (const float*)d_in[1];  // keypoint_desc  [4,64,400]
    const float* dd      = (const float*)d_in[2];  // desc_dense     [4,64,256,256]
    const int*   tgt_ids = (const int*)d_in[3];
    const int*   src_ids = (const int*)d_in[4];
    float* out = (float*)d_out;
    unsigned* wsu = (unsigned*)d_ws;
    float* part = (float*)d_ws + BFRAG_DW;

    prep_kernel <<<dim3(14, NPAIR),  256, 0, stream>>>(ksc, kd, tgt_ids, src_ids, wsu, out);
    match_kernel<<<dim3(512, NPAIR), 256, 0, stream>>>(dd, src_ids, wsu, part);
    merge_kernel<<<dim3(25, NPAIR),  256, 0, stream>>>(part, out);
}